// Round 2
// baseline (532.375 us; speedup 1.0000x reference)
//
#include <hip/hip_runtime.h>

#define Bz 8
#define Lz 2048
#define Dz 256
#define Nz 64
#define SP 68   // LDS row stride for 64x64 tiles: 16B-aligned rows, bank-spread

__device__ __forceinline__ float softplusf(float x) {
  return (x > 20.f) ? x : log1pf(expf(x));
}

// C = alpha*A*B (+ I if addI). 256 threads. Caller barriers before/after.
__device__ __forceinline__ void matmul64(float* __restrict__ Cb,
                                         const float* __restrict__ Ab,
                                         const float* __restrict__ Bb,
                                         float alpha, bool addI, int tid) {
  const int n = tid & 63, q = tid >> 6;
  float arow[64];
#pragma unroll
  for (int mm = 0; mm < 16; ++mm) {
    const float4 a4 = *(const float4*)(Ab + n * SP + mm * 4);
    arow[4 * mm + 0] = a4.x; arow[4 * mm + 1] = a4.y;
    arow[4 * mm + 2] = a4.z; arow[4 * mm + 3] = a4.w;
  }
  float acc[16];
#pragma unroll
  for (int i = 0; i < 16; ++i) acc[i] = 0.f;
  const float* Bq = Bb + q * 16;
#pragma unroll 8
  for (int m = 0; m < 64; ++m) {
    const float4 b0 = *(const float4*)(Bq + m * SP + 0);
    const float4 b1 = *(const float4*)(Bq + m * SP + 4);
    const float4 b2 = *(const float4*)(Bq + m * SP + 8);
    const float4 b3 = *(const float4*)(Bq + m * SP + 12);
    const float a = arow[m];
    acc[0]  = fmaf(a, b0.x, acc[0]);  acc[1]  = fmaf(a, b0.y, acc[1]);
    acc[2]  = fmaf(a, b0.z, acc[2]);  acc[3]  = fmaf(a, b0.w, acc[3]);
    acc[4]  = fmaf(a, b1.x, acc[4]);  acc[5]  = fmaf(a, b1.y, acc[5]);
    acc[6]  = fmaf(a, b1.z, acc[6]);  acc[7]  = fmaf(a, b1.w, acc[7]);
    acc[8]  = fmaf(a, b2.x, acc[8]);  acc[9]  = fmaf(a, b2.y, acc[9]);
    acc[10] = fmaf(a, b2.z, acc[10]); acc[11] = fmaf(a, b2.w, acc[11]);
    acc[12] = fmaf(a, b3.x, acc[12]); acc[13] = fmaf(a, b3.y, acc[13]);
    acc[14] = fmaf(a, b3.z, acc[14]); acc[15] = fmaf(a, b3.w, acc[15]);
  }
#pragma unroll
  for (int i = 0; i < 16; ++i) {
    const int c = q * 16 + i;
    Cb[n * SP + c] = alpha * acc[i] + ((addI && c == n) ? 1.f : 0.f);
  }
}

// One block per channel d: discretize (expm Taylor + scaling-squaring,
// dB = dt*phi1(A*dt)*Bp_d), then k[d,l] = C^T E^l dB via U/W chunking.
// Writes kT[l*Dz + d].
__global__ __launch_bounds__(256) void s4_build(
    const float* __restrict__ log_A, const float* __restrict__ Bp,
    const float* __restrict__ Cp, const float* __restrict__ log_delta,
    float* __restrict__ kT) {
  __shared__ alignas(16) float MB0[Nz * SP];
  __shared__ alignas(16) float MB1[Nz * SP];
  __shared__ alignas(16) float MB2[Nz * SP];
  __shared__ float vecv[Nz], vecterm[Nz], wvec[Nz];
  __shared__ float pr[4][Nz + 8];
  __shared__ float pr2[4][Nz + 8];
  __shared__ float scal;

  const int tid = threadIdx.x;
  const int d = blockIdx.x;
  const int n = tid & 63, q = tid >> 6;

  const float dt = softplusf(log_delta[d]) + 1e-6f;

  // M = softplus(log_A) * dt
  for (int idx = tid; idx < Nz * Nz; idx += 256) {
    const int r = idx >> 6, c = idx & 63;
    MB0[r * SP + c] = softplusf(log_A[idx]) * dt;
  }
  __syncthreads();

  // inf-norm of M -> scaling exponent s
  {
    float p = 0.f;
#pragma unroll
    for (int m0 = 0; m0 < 16; ++m0) p += fabsf(MB0[n * SP + q * 16 + m0]);
    pr[q][n] = p;
  }
  __syncthreads();
  if (tid < 64) {
    float rs = pr[0][tid] + pr[1][tid] + pr[2][tid] + pr[3][tid];
#pragma unroll
    for (int off = 32; off > 0; off >>= 1) rs = fmaxf(rs, __shfl_xor(rs, off));
    if (tid == 0) scal = rs;
  }
  __syncthreads();
  const float norm = scal;
  int s = 0;
  if (norm > 0.25f) {   // uniform branch
    s = (int)ceilf(log2f(norm * 4.0f));
    const float sc = exp2f((float)(-s));
    for (int idx = tid; idx < Nz * Nz; idx += 256) {
      const int r = idx >> 6, c = idx & 63;
      MB0[r * SP + c] *= sc;   // each element owned by one thread
    }
    __syncthreads();
  }

  // E = expm(M) via Taylor-6 Horner: P = I + M/6; P = I + M*P/k, k=5..1
  for (int idx = tid; idx < Nz * Nz; idx += 256) {
    const int r = idx >> 6, c = idx & 63;
    MB1[r * SP + c] = MB0[r * SP + c] * (1.f / 6.f) + ((r == c) ? 1.f : 0.f);
  }
  __syncthreads();
  float* P = MB1;
  float* T = MB2;
#pragma unroll 1
  for (int k = 5; k >= 1; --k) {
    matmul64(T, MB0, P, 1.f / (float)k, true, tid);
    __syncthreads();
    float* tswap = P; P = T; T = tswap;
  }

  // v = phi1(M)*Bp_d via Taylor matvecs: term_j = M*term_{j-1}/(j+1)
  if (tid < 64) {
    const float bv = Bp[d * Nz + tid];
    vecv[tid] = bv;
    vecterm[tid] = bv;
  }
  __syncthreads();
#pragma unroll 1
  for (int j = 1; j <= 6; ++j) {
    float p = 0.f;
#pragma unroll
    for (int m0 = 0; m0 < 16; ++m0) {
      const int m = q * 16 + m0;
      p += MB0[n * SP + m] * vecterm[m];
    }
    pr[q][n] = p;
    __syncthreads();
    if (tid < 64) {
      const float t = (pr[0][tid] + pr[1][tid] + pr[2][tid] + pr[3][tid]) / (float)(j + 1);
      vecterm[tid] = t;
      vecv[tid] += t;
    }
    __syncthreads();
  }

  // undo scaling: v <- 0.5*(E*v + v); E <- E*E   (s times; s==0 for this input)
  float* E = P;
  float* spare = T;
#pragma unroll 1
  for (int i = 0; i < s; ++i) {
    float p = 0.f;
#pragma unroll
    for (int m0 = 0; m0 < 16; ++m0) {
      const int m = q * 16 + m0;
      p += E[n * SP + m] * vecv[m];
    }
    pr[q][n] = p;
    __syncthreads();
    if (tid < 64)
      vecv[tid] = 0.5f * (pr[0][tid] + pr[1][tid] + pr[2][tid] + pr[3][tid] + vecv[tid]);
    __syncthreads();
    matmul64(spare, E, E, 1.f, false, tid);
    __syncthreads();
    float* tswap = E; E = spare; spare = tswap;
  }

  // U chain: U[:,0] = dt*v = dB; fill U[:, 2^j..2^{j+1}) = E^{2^j} * U[:,0..2^j)
  // interleaved with squarings; M (MB0) is dead -> reuse as U.
  float* const UB = MB0;
  if (tid < 64) UB[tid * SP + 0] = dt * vecv[tid];
  __syncthreads();
#pragma unroll 1
  for (int j = 0; j < 6; ++j) {
    const int c = 1 << j;
    for (int col = q; col < c; col += 4) {
      float p = 0.f;
#pragma unroll 16
      for (int m = 0; m < 64; ++m) p += E[n * SP + m] * UB[m * SP + col];
      UB[n * SP + c + col] = p;   // write cols >= c, read cols < c: disjoint
    }
    __syncthreads();
    matmul64(spare, E, E, 1.f, false, tid);
    __syncthreads();
    float* tswap = E; E = spare; spare = tswap;
  }
  // now E = E^64

  // W loop: w_0 = Cp_d; k[d,64j+r] = w_j . U[:,r]; w_{j+1} = E64^T w_j
  if (tid < 64) wvec[tid] = Cp[d * Nz + tid];
  __syncthreads();
  float* const kTd = kT + d;
#pragma unroll 1
  for (int j = 0; j < 32; ++j) {
    float pd = 0.f, pw = 0.f;
#pragma unroll
    for (int m0 = 0; m0 < 16; ++m0) {
      const int m = q * 16 + m0;
      pd += wvec[m] * UB[m * SP + n];   // dot for r = n
      pw += E[m * SP + n] * wvec[m];    // (E64^T w)[n]
    }
    pr[q][n] = pd;
    pr2[q][n] = pw;
    __syncthreads();
    if (tid < 64) {
      kTd[(size_t)(j * 64 + tid) * Dz] =
          pr[0][tid] + pr[1][tid] + pr[2][tid] + pr[3][tid];
      wvec[tid] = pr2[0][tid] + pr2[1][tid] + pr2[2][tid] + pr2[3][tid];
    }
    __syncthreads();
  }
}

// Split-k direct causal conv (pure conv part; skip fused into gemm).
// block (tt, b, j): j-th group of 8 source chunks; partials atomicAdd'ed
// into pre-zeroed yw. Register-rolled 63-tap k window (32 new taps/chunk).
__global__ __launch_bounds__(256, 4) void s4_conv(
    const float* __restrict__ x, const float* __restrict__ kT,
    float* __restrict__ yw) {
  const int d = threadIdx.x;
  const int tt = blockIdx.x;
  const int scBeg = blockIdx.z * 8;
  if (scBeg > tt) return;
  const int b = blockIdx.y;
  const int scEnd = min(tt + 1, scBeg + 8);
  const int t0 = tt * 32;
  const float* xb = x + ((size_t)b * Lz) * Dz + d;
  const float* kd = kT + d;

  float acc[32];
#pragma unroll
  for (int i = 0; i < 32; ++i) acc[i] = 0.f;

  int base = t0 - scBeg * 32;  // largest base first; decreases by 32 per chunk
  float kw[63];                // kw[u] = k[base-31+u], zero for idx<0
#pragma unroll
  for (int u = 0; u < 63; ++u) {
    const int idx = base - 31 + u;
    kw[u] = (idx >= 0) ? kd[(size_t)idx * Dz] : 0.f;
  }

  for (int sc = scBeg;;) {
    const int s0 = sc * 32;
#pragma unroll
    for (int jj = 0; jj < 32; ++jj) {
      const float xv = xb[(size_t)(s0 + jj) * Dz];
#pragma unroll
      for (int i = 0; i < 32; ++i)
        acc[i] = fmaf(kw[i - jj + 31], xv, acc[i]);
    }
    ++sc;
    if (sc >= scEnd) break;
    base -= 32;
    // roll window: new kw[u] = k[base-31+u]; upper 31 come from old lower
#pragma unroll
    for (int u = 62; u >= 32; --u) kw[u] = kw[u - 32];
#pragma unroll
    for (int u = 0; u < 32; ++u) {
      const int idx = base - 31 + u;
      kw[u] = (idx >= 0) ? kd[(size_t)idx * Dz] : 0.f;
    }
  }

  float* ywp = yw + ((size_t)blockIdx.y * Lz + t0) * Dz + d;
#pragma unroll
  for (int i = 0; i < 32; ++i)
    atomicAdd(ywp + (size_t)i * Dz, acc[i]);
}

// out[r,c] = sum_d (yw[r,d] + x[r,d]*skip[d]) * W[c,d] + b[c]
// LDS-tiled 64x64, 4x4 microtile.
__global__ __launch_bounds__(256) void s4_gemm(
    const float* __restrict__ yw, const float* __restrict__ x,
    const float* __restrict__ skip_D, const float* __restrict__ Wo,
    const float* __restrict__ bo, float* __restrict__ out) {
  __shared__ alignas(16) float Ys[64 * 17];
  __shared__ alignas(16) float Ws[64 * 17];
  const int tid = threadIdx.x;
  const int r0 = blockIdx.x * 64;
  const int c0 = blockIdx.y * 64;
  const int tr = tid >> 4, tc = tid & 15;
  const int lr = tid >> 2, lq = tid & 3;
  float acc[16];
#pragma unroll
  for (int i = 0; i < 16; ++i) acc[i] = 0.f;
  for (int kc = 0; kc < 16; ++kc) {
    const int dc0 = kc * 16;
    const float4 ya = *(const float4*)(yw + (size_t)(r0 + lr) * Dz + dc0 + lq * 4);
    const float4 xa = *(const float4*)(x + (size_t)(r0 + lr) * Dz + dc0 + lq * 4);
    const float4 sk = *(const float4*)(skip_D + dc0 + lq * 4);
    const float4 wa = *(const float4*)(Wo + (size_t)(c0 + lr) * Dz + dc0 + lq * 4);
    Ys[lr * 17 + lq * 4 + 0] = ya.x + xa.x * sk.x;
    Ys[lr * 17 + lq * 4 + 1] = ya.y + xa.y * sk.y;
    Ys[lr * 17 + lq * 4 + 2] = ya.z + xa.z * sk.z;
    Ys[lr * 17 + lq * 4 + 3] = ya.w + xa.w * sk.w;
    Ws[lr * 17 + lq * 4 + 0] = wa.x; Ws[lr * 17 + lq * 4 + 1] = wa.y;
    Ws[lr * 17 + lq * 4 + 2] = wa.z; Ws[lr * 17 + lq * 4 + 3] = wa.w;
    __syncthreads();
#pragma unroll
    for (int dk = 0; dk < 16; ++dk) {
      float yv[4], wv[4];
#pragma unroll
      for (int i = 0; i < 4; ++i) yv[i] = Ys[(tr * 4 + i) * 17 + dk];
#pragma unroll
      for (int i = 0; i < 4; ++i) wv[i] = Ws[(tc * 4 + i) * 17 + dk];
#pragma unroll
      for (int i = 0; i < 4; ++i)
#pragma unroll
        for (int jj = 0; jj < 4; ++jj)
          acc[i * 4 + jj] = fmaf(yv[i], wv[jj], acc[i * 4 + jj]);
    }
    __syncthreads();
  }
#pragma unroll
  for (int i = 0; i < 4; ++i)
#pragma unroll
    for (int jj = 0; jj < 4; ++jj) {
      const int cc = c0 + tc * 4 + jj;
      out[(size_t)(r0 + tr * 4 + i) * Dz + cc] = acc[i * 4 + jj] + bo[cc];
    }
}

extern "C" void kernel_launch(void* const* d_in, const int* in_sizes, int n_in,
                              void* d_out, int out_size, void* d_ws, size_t ws_size,
                              hipStream_t stream) {
  const float* x         = (const float*)d_in[0];
  const float* log_A     = (const float*)d_in[1];
  const float* Bp        = (const float*)d_in[2];
  const float* Cp        = (const float*)d_in[3];
  const float* log_delta = (const float*)d_in[4];
  const float* skip_D    = (const float*)d_in[5];
  const float* W_out     = (const float*)d_in[6];
  const float* b_out     = (const float*)d_in[7];
  float* out = (float*)d_out;

  // workspace: kT [Lz*Dz] then yw [Bz*Lz*Dz]  (~18.9 MB total)
  float* kT = (float*)d_ws;
  float* yw = kT + (size_t)Lz * Dz;

  hipLaunchKernelGGL(s4_build, dim3(Dz), dim3(256), 0, stream,
                     log_A, Bp, Cp, log_delta, kT);
  hipMemsetAsync(yw, 0, sizeof(float) * (size_t)Bz * Lz * Dz, stream);
  hipLaunchKernelGGL(s4_conv, dim3(Lz / 32, Bz, 8), dim3(256), 0, stream,
                     x, kT, yw);
  hipLaunchKernelGGL(s4_gemm, dim3((Bz * Lz) / 64, Dz / 64), dim3(256), 0, stream,
                     yw, x, skip_D, W_out, b_out, out);
}

// Round 3
// 416.168 us; speedup vs baseline: 1.2792x; 1.2792x over previous
//
#include <hip/hip_runtime.h>

#define Bz 8
#define Lz 2048
#define Dz 256
#define Nz 64
#define SP 68   // LDS row stride for 64x64 tiles: 16B-aligned rows, bank-spread

__device__ __forceinline__ float softplusf(float x) {
  return (x > 20.f) ? x : log1pf(expf(x));
}

// C = alpha*A*B (+ I if addI). 256 threads. Caller barriers before/after.
__device__ __forceinline__ void matmul64(float* __restrict__ Cb,
                                         const float* __restrict__ Ab,
                                         const float* __restrict__ Bb,
                                         float alpha, bool addI, int tid) {
  const int n = tid & 63, q = tid >> 6;
  float arow[64];
#pragma unroll
  for (int mm = 0; mm < 16; ++mm) {
    const float4 a4 = *(const float4*)(Ab + n * SP + mm * 4);
    arow[4 * mm + 0] = a4.x; arow[4 * mm + 1] = a4.y;
    arow[4 * mm + 2] = a4.z; arow[4 * mm + 3] = a4.w;
  }
  float acc[16];
#pragma unroll
  for (int i = 0; i < 16; ++i) acc[i] = 0.f;
  const float* Bq = Bb + q * 16;
#pragma unroll 8
  for (int m = 0; m < 64; ++m) {
    const float4 b0 = *(const float4*)(Bq + m * SP + 0);
    const float4 b1 = *(const float4*)(Bq + m * SP + 4);
    const float4 b2 = *(const float4*)(Bq + m * SP + 8);
    const float4 b3 = *(const float4*)(Bq + m * SP + 12);
    const float a = arow[m];
    acc[0]  = fmaf(a, b0.x, acc[0]);  acc[1]  = fmaf(a, b0.y, acc[1]);
    acc[2]  = fmaf(a, b0.z, acc[2]);  acc[3]  = fmaf(a, b0.w, acc[3]);
    acc[4]  = fmaf(a, b1.x, acc[4]);  acc[5]  = fmaf(a, b1.y, acc[5]);
    acc[6]  = fmaf(a, b1.z, acc[6]);  acc[7]  = fmaf(a, b1.w, acc[7]);
    acc[8]  = fmaf(a, b2.x, acc[8]);  acc[9]  = fmaf(a, b2.y, acc[9]);
    acc[10] = fmaf(a, b2.z, acc[10]); acc[11] = fmaf(a, b2.w, acc[11]);
    acc[12] = fmaf(a, b3.x, acc[12]); acc[13] = fmaf(a, b3.y, acc[13]);
    acc[14] = fmaf(a, b3.z, acc[14]); acc[15] = fmaf(a, b3.w, acc[15]);
  }
#pragma unroll
  for (int i = 0; i < 16; ++i) {
    const int c = q * 16 + i;
    Cb[n * SP + c] = alpha * acc[i] + ((addI && c == n) ? 1.f : 0.f);
  }
}

// One block per channel d: discretize (expm Taylor + scaling-squaring,
// dB = dt*phi1(A*dt)*Bp_d), then k[d,l] = C^T E^l dB via U/W chunking.
// Writes kT[l*Dz + d].
__global__ __launch_bounds__(256) void s4_build(
    const float* __restrict__ log_A, const float* __restrict__ Bp,
    const float* __restrict__ Cp, const float* __restrict__ log_delta,
    float* __restrict__ kT) {
  __shared__ alignas(16) float MB0[Nz * SP];
  __shared__ alignas(16) float MB1[Nz * SP];
  __shared__ alignas(16) float MB2[Nz * SP];
  __shared__ float vecv[Nz], vecterm[Nz], wvec[Nz];
  __shared__ float pr[4][Nz + 8];
  __shared__ float pr2[4][Nz + 8];
  __shared__ float scal;

  const int tid = threadIdx.x;
  const int d = blockIdx.x;
  const int n = tid & 63, q = tid >> 6;

  const float dt = softplusf(log_delta[d]) + 1e-6f;

  // M = softplus(log_A) * dt
  for (int idx = tid; idx < Nz * Nz; idx += 256) {
    const int r = idx >> 6, c = idx & 63;
    MB0[r * SP + c] = softplusf(log_A[idx]) * dt;
  }
  __syncthreads();

  // inf-norm of M -> scaling exponent s
  {
    float p = 0.f;
#pragma unroll
    for (int m0 = 0; m0 < 16; ++m0) p += fabsf(MB0[n * SP + q * 16 + m0]);
    pr[q][n] = p;
  }
  __syncthreads();
  if (tid < 64) {
    float rs = pr[0][tid] + pr[1][tid] + pr[2][tid] + pr[3][tid];
#pragma unroll
    for (int off = 32; off > 0; off >>= 1) rs = fmaxf(rs, __shfl_xor(rs, off));
    if (tid == 0) scal = rs;
  }
  __syncthreads();
  const float norm = scal;
  int s = 0;
  if (norm > 0.25f) {   // uniform branch
    s = (int)ceilf(log2f(norm * 4.0f));
    const float sc = exp2f((float)(-s));
    for (int idx = tid; idx < Nz * Nz; idx += 256) {
      const int r = idx >> 6, c = idx & 63;
      MB0[r * SP + c] *= sc;   // each element owned by one thread
    }
    __syncthreads();
  }

  // E = expm(M) via Taylor-6 Horner: P = I + M/6; P = I + M*P/k, k=5..1
  for (int idx = tid; idx < Nz * Nz; idx += 256) {
    const int r = idx >> 6, c = idx & 63;
    MB1[r * SP + c] = MB0[r * SP + c] * (1.f / 6.f) + ((r == c) ? 1.f : 0.f);
  }
  __syncthreads();
  float* P = MB1;
  float* T = MB2;
#pragma unroll 1
  for (int k = 5; k >= 1; --k) {
    matmul64(T, MB0, P, 1.f / (float)k, true, tid);
    __syncthreads();
    float* tswap = P; P = T; T = tswap;
  }

  // v = phi1(M)*Bp_d via Taylor matvecs: term_j = M*term_{j-1}/(j+1)
  if (tid < 64) {
    const float bv = Bp[d * Nz + tid];
    vecv[tid] = bv;
    vecterm[tid] = bv;
  }
  __syncthreads();
#pragma unroll 1
  for (int j = 1; j <= 6; ++j) {
    float p = 0.f;
#pragma unroll
    for (int m0 = 0; m0 < 16; ++m0) {
      const int m = q * 16 + m0;
      p += MB0[n * SP + m] * vecterm[m];
    }
    pr[q][n] = p;
    __syncthreads();
    if (tid < 64) {
      const float t = (pr[0][tid] + pr[1][tid] + pr[2][tid] + pr[3][tid]) / (float)(j + 1);
      vecterm[tid] = t;
      vecv[tid] += t;
    }
    __syncthreads();
  }

  // undo scaling: v <- 0.5*(E*v + v); E <- E*E   (s times; s==0 for this input)
  float* E = P;
  float* spare = T;
#pragma unroll 1
  for (int i = 0; i < s; ++i) {
    float p = 0.f;
#pragma unroll
    for (int m0 = 0; m0 < 16; ++m0) {
      const int m = q * 16 + m0;
      p += E[n * SP + m] * vecv[m];
    }
    pr[q][n] = p;
    __syncthreads();
    if (tid < 64)
      vecv[tid] = 0.5f * (pr[0][tid] + pr[1][tid] + pr[2][tid] + pr[3][tid] + vecv[tid]);
    __syncthreads();
    matmul64(spare, E, E, 1.f, false, tid);
    __syncthreads();
    float* tswap = E; E = spare; spare = tswap;
  }

  // U chain: U[:,0] = dt*v = dB; fill U[:, 2^j..2^{j+1}) = E^{2^j} * U[:,0..2^j)
  // interleaved with squarings; M (MB0) is dead -> reuse as U.
  float* const UB = MB0;
  if (tid < 64) UB[tid * SP + 0] = dt * vecv[tid];
  __syncthreads();
#pragma unroll 1
  for (int j = 0; j < 6; ++j) {
    const int c = 1 << j;
    for (int col = q; col < c; col += 4) {
      float p = 0.f;
#pragma unroll 16
      for (int m = 0; m < 64; ++m) p += E[n * SP + m] * UB[m * SP + col];
      UB[n * SP + c + col] = p;   // write cols >= c, read cols < c: disjoint
    }
    __syncthreads();
    matmul64(spare, E, E, 1.f, false, tid);
    __syncthreads();
    float* tswap = E; E = spare; spare = tswap;
  }
  // now E = E^64

  // W loop: w_0 = Cp_d; k[d,64j+r] = w_j . U[:,r]; w_{j+1} = E64^T w_j
  if (tid < 64) wvec[tid] = Cp[d * Nz + tid];
  __syncthreads();
  float* const kTd = kT + d;
#pragma unroll 1
  for (int j = 0; j < 32; ++j) {
    float pd = 0.f, pw = 0.f;
#pragma unroll
    for (int m0 = 0; m0 < 16; ++m0) {
      const int m = q * 16 + m0;
      pd += wvec[m] * UB[m * SP + n];   // dot for r = n
      pw += E[m * SP + n] * wvec[m];    // (E64^T w)[n]
    }
    pr[q][n] = pd;
    pr2[q][n] = pw;
    __syncthreads();
    if (tid < 64) {
      kTd[(size_t)(j * 64 + tid) * Dz] =
          pr[0][tid] + pr[1][tid] + pr[2][tid] + pr[3][tid];
      wvec[tid] = pr2[0][tid] + pr2[1][tid] + pr2[2][tid] + pr2[3][tid];
    }
    __syncthreads();
  }
}

// Balanced causal conv. Block = 512 threads (d = tid&255, half = tid>>8),
// handles output tiles tt=p and tt=63-p (uniform 65 chunk-passes/block).
// Within a tile the two halves split the source chunks (split-k) and the
// partials are combined through LDS (no atomics). Register-rolled k window.
__global__ __launch_bounds__(512, 2) void s4_conv(
    const float* __restrict__ x, const float* __restrict__ kT,
    float* __restrict__ yw) {
  __shared__ float part[32][Dz];
  const int d = threadIdx.x & 255;
  const int half = threadIdx.x >> 8;
  const int p = blockIdx.x;
  const int b = blockIdx.y;
  const float* xb = x + ((size_t)b * Lz) * Dz + d;
  const float* kd = kT + d;

#pragma unroll 1
  for (int tile = 0; tile < 2; ++tile) {
    const int tt = tile ? (63 - p) : p;
    const int t0 = tt * 32;
    const int nch = tt + 1;
    const int h0 = (nch + 1) >> 1;              // half0: [0,h0)  half1: [h0,nch)
    const int beg = half ? h0 : 0;
    const int end = half ? nch : h0;

    float acc[32];
#pragma unroll
    for (int i = 0; i < 32; ++i) acc[i] = 0.f;

    if (beg < end) {
      int base = t0 - beg * 32;                 // decreases by 32 per chunk
      float kw[63];                             // kw[u] = k[base-31+u]
#pragma unroll
      for (int u = 0; u < 63; ++u) {
        const int idx = base - 31 + u;
        kw[u] = (idx >= 0) ? kd[(size_t)idx * Dz] : 0.f;
      }
      for (int sc = beg;;) {
        const int s0 = sc * 32;
#pragma unroll
        for (int jj = 0; jj < 32; ++jj) {
          const float xv = xb[(size_t)(s0 + jj) * Dz];
#pragma unroll
          for (int i = 0; i < 32; ++i)
            acc[i] = fmaf(kw[i - jj + 31], xv, acc[i]);
        }
        ++sc;
        if (sc >= end) break;
        base -= 32;
#pragma unroll
        for (int u = 62; u >= 32; --u) kw[u] = kw[u - 32];
#pragma unroll
        for (int u = 0; u < 32; ++u) {
          const int idx = base - 31 + u;
          kw[u] = (idx >= 0) ? kd[(size_t)idx * Dz] : 0.f;
        }
      }
    }

    // combine halves through LDS, half0 stores
    if (half == 1) {
#pragma unroll
      for (int i = 0; i < 32; ++i) part[i][d] = acc[i];
    }
    __syncthreads();
    if (half == 0) {
      float* ywp = yw + ((size_t)b * Lz + t0) * Dz + d;
#pragma unroll
      for (int i = 0; i < 32; ++i)
        ywp[(size_t)i * Dz] = acc[i] + part[i][d];
    }
    __syncthreads();   // LDS reused by next tile
  }
}

// out[r,c] = sum_d (yw[r,d] + x[r,d]*skip[d]) * W[c,d] + b[c]
// LDS-tiled 64x64, 4x4 microtile.
__global__ __launch_bounds__(256) void s4_gemm(
    const float* __restrict__ yw, const float* __restrict__ x,
    const float* __restrict__ skip_D, const float* __restrict__ Wo,
    const float* __restrict__ bo, float* __restrict__ out) {
  __shared__ alignas(16) float Ys[64 * 17];
  __shared__ alignas(16) float Ws[64 * 17];
  const int tid = threadIdx.x;
  const int r0 = blockIdx.x * 64;
  const int c0 = blockIdx.y * 64;
  const int tr = tid >> 4, tc = tid & 15;
  const int lr = tid >> 2, lq = tid & 3;
  float acc[16];
#pragma unroll
  for (int i = 0; i < 16; ++i) acc[i] = 0.f;
  for (int kc = 0; kc < 16; ++kc) {
    const int dc0 = kc * 16;
    const float4 ya = *(const float4*)(yw + (size_t)(r0 + lr) * Dz + dc0 + lq * 4);
    const float4 xa = *(const float4*)(x + (size_t)(r0 + lr) * Dz + dc0 + lq * 4);
    const float4 sk = *(const float4*)(skip_D + dc0 + lq * 4);
    const float4 wa = *(const float4*)(Wo + (size_t)(c0 + lr) * Dz + dc0 + lq * 4);
    Ys[lr * 17 + lq * 4 + 0] = ya.x + xa.x * sk.x;
    Ys[lr * 17 + lq * 4 + 1] = ya.y + xa.y * sk.y;
    Ys[lr * 17 + lq * 4 + 2] = ya.z + xa.z * sk.z;
    Ys[lr * 17 + lq * 4 + 3] = ya.w + xa.w * sk.w;
    Ws[lr * 17 + lq * 4 + 0] = wa.x; Ws[lr * 17 + lq * 4 + 1] = wa.y;
    Ws[lr * 17 + lq * 4 + 2] = wa.z; Ws[lr * 17 + lq * 4 + 3] = wa.w;
    __syncthreads();
#pragma unroll
    for (int dk = 0; dk < 16; ++dk) {
      float yv[4], wv[4];
#pragma unroll
      for (int i = 0; i < 4; ++i) yv[i] = Ys[(tr * 4 + i) * 17 + dk];
#pragma unroll
      for (int i = 0; i < 4; ++i) wv[i] = Ws[(tc * 4 + i) * 17 + dk];
#pragma unroll
      for (int i = 0; i < 4; ++i)
#pragma unroll
        for (int jj = 0; jj < 4; ++jj)
          acc[i * 4 + jj] = fmaf(yv[i], wv[jj], acc[i * 4 + jj]);
    }
    __syncthreads();
  }
#pragma unroll
  for (int i = 0; i < 4; ++i)
#pragma unroll
    for (int jj = 0; jj < 4; ++jj) {
      const int cc = c0 + tc * 4 + jj;
      out[(size_t)(r0 + tr * 4 + i) * Dz + cc] = acc[i * 4 + jj] + bo[cc];
    }
}

extern "C" void kernel_launch(void* const* d_in, const int* in_sizes, int n_in,
                              void* d_out, int out_size, void* d_ws, size_t ws_size,
                              hipStream_t stream) {
  const float* x         = (const float*)d_in[0];
  const float* log_A     = (const float*)d_in[1];
  const float* Bp        = (const float*)d_in[2];
  const float* Cp        = (const float*)d_in[3];
  const float* log_delta = (const float*)d_in[4];
  const float* skip_D    = (const float*)d_in[5];
  const float* W_out     = (const float*)d_in[6];
  const float* b_out     = (const float*)d_in[7];
  float* out = (float*)d_out;

  // workspace: kT [Lz*Dz] then yw [Bz*Lz*Dz]  (~18.9 MB total)
  float* kT = (float*)d_ws;
  float* yw = kT + (size_t)Lz * Dz;

  hipLaunchKernelGGL(s4_build, dim3(Dz), dim3(256), 0, stream,
                     log_A, Bp, Cp, log_delta, kT);
  hipLaunchKernelGGL(s4_conv, dim3(32, Bz), dim3(512), 0, stream,
                     x, kT, yw);
  hipLaunchKernelGGL(s4_gemm, dim3((Bz * Lz) / 64, Dz / 64), dim3(256), 0, stream,
                     yw, x, skip_D, W_out, b_out, out);
}